// Round 10
// baseline (64.359 us; speedup 1.0000x reference)
//
#include <hip/hip_runtime.h>
#include <hip/hip_bf16.h>

typedef unsigned short u16;
typedef __bf16 bf16x8 __attribute__((ext_vector_type(8)));
typedef float f32x4 __attribute__((ext_vector_type(4)));
typedef float f32x16 __attribute__((ext_vector_type(16)));
typedef unsigned short ushort8 __attribute__((ext_vector_type(8)));

#define C_IN   128
#define C_OUT  256
#define BATCH  16
#define LEN    4096
#define KS     9
#define PAD    4
#define LPAD   (LEN + 2*PAD)      // 4104
#define KTOT   (C_IN * KS)        // 1152
#define NSTEP  72                 // K = 1152 / 16

#define XT_BLKS    1040           // 65 * 16
#define W5_BLKS    1152           // 294912 / 256
#define EB_BLKS    256

__device__ inline u16 f2bf(float f) {
    __hip_bfloat16 h = __float2bfloat16(f);
    return __builtin_bit_cast(u16, h);
}

// async global->LDS, 16B per lane, wave-uniform LDS base + lane*16
__device__ __forceinline__ void g2l16(const void* g, void* l) {
    __builtin_amdgcn_global_load_lds(
        (const __attribute__((address_space(1))) void*)g,
        (__attribute__((address_space(3))) void*)l, 16, 0, 0);
}

// ---------------------------------------------------------------------------
// Fused prep (one launch):
//  blocks [0,1040): x [B][C][L] f32 -> xt [B][LPAD][C] bf16, edge-padded,
//    4-bit XOR swizzle (16B-block idx ^= l&15) baked into global layout.
//  blocks [1040,2192): weight -> w5 in 32-lane fragment order for
//    mfma_f32_32x32x16_bf16:  i = ((s*8 + g)*64 + lane)*8 + e  where
//    o = g*32 + (lane&31), hi = lane>>5, c = (s&7)*16 + hi*8 + e, k = s>>3.
//  blocks [2192,2448): ebias[o] = bias[o] + sum offset*W; block 2192: phys.
// ---------------------------------------------------------------------------
__global__ void prep_all(const float* __restrict__ x, const float* __restrict__ w,
                         const float* __restrict__ bias, const float* __restrict__ vel,
                         const float* __restrict__ acc_in,
                         u16* __restrict__ xt, u16* __restrict__ w5,
                         float* __restrict__ ebias, float* __restrict__ phys_out) {
    int bid = blockIdx.x;
    int t = threadIdx.x;
    if (bid < XT_BLKS) {
        int b    = bid / 65;
        int lblk = bid % 65;
        int lane = t & 63;
        int jb   = t >> 6;
        int lp   = lblk * 64 + lane;
        if (lp >= LPAD) return;
        int l = lp - PAD;
        l = l < 0 ? 0 : (l > LEN - 1 ? LEN - 1 : l);
        const float* xb = x + (size_t)b * C_IN * LEN + l;
        u16* row = xt + ((size_t)b * LPAD + lp) * C_IN;
        int key = lp & 15;
        #pragma unroll
        for (int jj = 0; jj < 4; ++jj) {
            int cblk = jb * 4 + jj;
            ushort8 v;
            #pragma unroll
            for (int e = 0; e < 8; ++e)
                v[e] = f2bf(xb[(size_t)(cblk * 8 + e) * LEN]);
            int jstore = cblk ^ key;
            *reinterpret_cast<ushort8*>(row + jstore * 8) = v;
        }
        return;
    }
    if (bid < XT_BLKS + W5_BLKS) {
        int i = (bid - XT_BLKS) * 256 + t;   // 294912 total
        int e    = i & 7;
        int lane = (i >> 3) & 63;
        int g    = (i >> 9) & 7;
        int s    = i >> 12;                  // 0..71
        int o    = g * 32 + (lane & 31);
        int hi   = lane >> 5;
        int c    = (s & 7) * 16 + hi * 8 + e;
        int k    = s >> 3;
        w5[i] = f2bf(w[((size_t)o * C_IN + c) * KS + k]);
        return;
    }
    __shared__ float red[256];
    int o = bid - (XT_BLKS + W5_BLKS);
    float sum = 0.f;
    for (int i = t; i < KTOT; i += 256) {
        int k = i % KS;                    // offset layout [c][k]
        float tk = k * 0.01f;              // DT
        float off = vel[i] * tk + 0.5f * acc_in[i] * tk * tk;
        sum += off * w[(size_t)o * KTOT + i];
    }
    red[t] = sum;
    __syncthreads();
    for (int h = 128; h > 0; h >>= 1) {
        if (t < h) red[t] += red[t + h];
        __syncthreads();
    }
    if (t == 0) ebias[o] = bias[o] + red[0];

    if (o == 0) {                          // phys
        __syncthreads();
        float pv = 0.f;
        for (int i = t; i < KTOT; i += 256) {
            float v = vel[i], a = acc_in[i];
            pv += v * v + a * a;
        }
        red[t] = pv;
        __syncthreads();
        for (int h = 128; h > 0; h >>= 1) {
            if (t < h) red[t] += red[t + h];
            __syncthreads();
        }
        if (t == 0) *phys_out = 0.01f * (red[0] / (float)KTOT);
    }
}

// ---------------------------------------------------------------------------
// Main: implicit-GEMM conv, mfma_f32_32x32x16_bf16, TRUE counted-vmcnt
// pipeline (T4 done right this time):
//   ring-4 A buffers, stage distance 3, register prefetch distance 1,
//   ONE barrier per step, vmcnt(2) BEFORE the barrier (never 0 mid-loop).
// Invariant: at end of step e, only stage(e+3) is outstanding (2 calls/wave)
// => stage(e+2) landed => step e+1's ds_reads of buf (e+2)%4 are safe.
// Cross-wave safety: every wave's own vmcnt precedes the barrier, and reads
// happen after it, so all waves' staged portions are published (m201 rule).
// WAR safety: stage(s+3) targets buf (s-1)%4, whose reads (issued at s-2)
// drained before MFMA(s-1) < barrier(s-1) < stage issue at s.
// Block = 256 o x 128 l, 4 waves (2 wm x 2 wn), wave tile 128 o x 64 l.
// LDS = 36864 (B, 144 rows for uniform 9-call staging) + 4x8192 = 69632 B
// -> 2 blocks/CU; setprio(1) around MFMA cluster (2 drifting blocks give
// the scheduler role diversity).
// ---------------------------------------------------------------------------
__global__ __launch_bounds__(256, 2) void conv_main(const u16* __restrict__ xt,
                                                    const u16* __restrict__ w5,
                                                    const float* __restrict__ ebias,
                                                    float* __restrict__ out) {
    __shared__ u16 ldsx[18432];            // B tile: 144 rows x 256B = 36864 B
    __shared__ u16 ldsa[4][4096];          // A ring: 4 x 8192 B

    int b     = blockIdx.y;
    int lbase = blockIdx.x * 128;
    int t     = threadIdx.x;
    int lane  = t & 63;
    int w     = t >> 6;
    int wm    = w >> 1;                    // o-half (128 o per wave)
    int wn    = w & 1;                     // l-half (64 l per wave)
    int l31   = lane & 31;
    int hi    = lane >> 5;

    // ---- prologue: stage B (144 rows, 9 uniform calls/wave) + A(0..2)
    {
        const u16* bsrc = xt + ((size_t)b * LPAD + lbase) * C_IN;
        #pragma unroll
        for (int j = 0; j < 9; ++j)        // rows 136..143 are pad (never read)
            g2l16(bsrc + (j * 256 + t) * 8, ldsx + (j * 256 + w * 64) * 8);
        #pragma unroll
        for (int p = 0; p < 3; ++p)
            #pragma unroll
            for (int j = 0; j < 2; ++j)
                g2l16(w5 + (size_t)p * 4096 + (j * 256 + t) * 8,
                      ldsa[p] + (j * 256 + w * 64) * 8);
    }
    // leave A(2) in flight; B + A(0) + A(1) landed (needed by steps 0 and 1)
    asm volatile("s_waitcnt vmcnt(2)" ::: "memory");
    __builtin_amdgcn_s_barrier();

    f32x16 acc[4][2] = {};
    const char* ldsbase = reinterpret_cast<const char*>(ldsx);

    #define LOAD_A(BUF, AF)                                                      \
        {                                                                        \
            const u16* ab_ = ldsa[BUF] + ((wm * 4) * 64 + lane) * 8;             \
            _Pragma("unroll")                                                    \
            for (int mi = 0; mi < 4; ++mi)                                       \
                AF[mi] = *reinterpret_cast<const bf16x8*>(ab_ + mi * 512);       \
        }
    #define LOAD_B(S, BF)                                                        \
        {                                                                        \
            int k_ = (S) >> 3;                                                   \
            int sl_ = ((S) & 7) * 2 + hi;                                        \
            _Pragma("unroll")                                                    \
            for (int nj = 0; nj < 2; ++nj) {                                     \
                int row_  = wn * 64 + nj * 32 + l31 + k_;                        \
                int addr_ = row_ * 256 + ((sl_ ^ (row_ & 15)) << 4);             \
                BF[nj] = *reinterpret_cast<const bf16x8*>(ldsbase + addr_);      \
            }                                                                    \
        }
    #define STAGE_A(S)                                                           \
        {                                                                        \
            const u16* as_ = w5 + (size_t)(S) * 4096;                            \
            u16* ad_ = ldsa[(S) & 3];                                            \
            _Pragma("unroll")                                                    \
            for (int j = 0; j < 2; ++j)                                          \
                g2l16(as_ + (j * 256 + t) * 8, ad_ + (j * 256 + w * 64) * 8);    \
        }
    #define MFMA8(AF, BF)                                                        \
        {                                                                        \
            _Pragma("unroll")                                                    \
            for (int mi = 0; mi < 4; ++mi)                                       \
                _Pragma("unroll")                                                \
                for (int nj = 0; nj < 2; ++nj)                                   \
                    acc[mi][nj] = __builtin_amdgcn_mfma_f32_32x32x16_bf16(       \
                        AF[mi], BF[nj], acc[mi][nj], 0, 0, 0);                   \
        }
    // end-of-step wait: for e<=68 leave only stage(e+3) in flight -> vmcnt(2);
    // e=69,70 have no later stages -> drain to 0 (cheap, tail only)
    #define ENDSTEP(E)                                                           \
        {                                                                        \
            if ((E) + 3 < NSTEP) asm volatile("s_waitcnt vmcnt(2)" ::: "memory");\
            else                 asm volatile("s_waitcnt vmcnt(0)" ::: "memory");\
            __builtin_amdgcn_s_barrier();                                        \
        }

    bf16x8 aA[4], aB[4], bA[2], bB[2];
    LOAD_A(0, aA);
    LOAD_B(0, bA);

    #pragma unroll
    for (int s = 0; s < NSTEP; s += 2) {
        // ---- even step s (regs A) ----
        if (s + 3 < NSTEP) STAGE_A(s + 3);
        LOAD_A((s + 1) & 3, aB);           // stage(s+1) landed per invariant
        LOAD_B(s + 1, bB);
        __builtin_amdgcn_s_setprio(1);
        MFMA8(aA, bA);
        __builtin_amdgcn_s_setprio(0);
        ENDSTEP(s);
        // ---- odd step s+1 (regs B) ----
        if (s + 4 < NSTEP) STAGE_A(s + 4);
        if (s + 2 < NSTEP) { LOAD_A((s + 2) & 3, aA); LOAD_B(s + 2, bA); }
        __builtin_amdgcn_s_setprio(1);
        MFMA8(aB, bB);
        __builtin_amdgcn_s_setprio(0);
        if (s + 2 < NSTEP) ENDSTEP(s + 1);
    }

    // ---- epilogue: 32x32 D layout col = lane&31, row = (reg&3)+8*(reg>>2)+4*hi
    #pragma unroll
    for (int mi = 0; mi < 4; ++mi) {
        #pragma unroll
        for (int nj = 0; nj < 2; ++nj) {
            int o0 = wm * 128 + mi * 32 + hi * 4;
            int l  = lbase + wn * 64 + nj * 32 + l31;
            #pragma unroll
            for (int q = 0; q < 4; ++q) {
                f32x4 eb = *reinterpret_cast<const f32x4*>(ebias + o0 + q * 8);
                float* op = out + (size_t)(b * C_OUT + o0 + q * 8) * LEN + l;
                #pragma unroll
                for (int p = 0; p < 4; ++p)
                    op[(size_t)p * LEN] = acc[mi][nj][q * 4 + p] + eb[p];
            }
        }
    }
    #undef LOAD_A
    #undef LOAD_B
    #undef STAGE_A
    #undef MFMA8
    #undef ENDSTEP
}

extern "C" void kernel_launch(void* const* d_in, const int* in_sizes, int n_in,
                              void* d_out, int out_size, void* d_ws, size_t ws_size,
                              hipStream_t stream) {
    const float* x      = (const float*)d_in[0];
    const float* weight = (const float*)d_in[1];
    const float* bias   = (const float*)d_in[2];
    const float* vel    = (const float*)d_in[3];
    const float* acc    = (const float*)d_in[4];
    float* out = (float*)d_out;

    char* ws = (char*)d_ws;
    u16*  xt    = (u16*)ws;                                       // 16,797,696 B
    u16*  w5    = (u16*)(ws + (size_t)BATCH * LPAD * C_IN * 2);   // 589,824 B
    float* ebias = (float*)(ws + (size_t)BATCH * LPAD * C_IN * 2 + (size_t)C_OUT * KTOT * 2);

    hipLaunchKernelGGL(prep_all, dim3(XT_BLKS + W5_BLKS + EB_BLKS), dim3(256), 0, stream,
                       x, weight, bias, vel, acc, xt, w5, ebias,
                       out + (size_t)BATCH * C_OUT * LEN);
    hipLaunchKernelGGL(conv_main, dim3(LEN / 128, BATCH), dim3(256), 0, stream,
                       xt, w5, ebias, out);
}

// Round 11
// 57.638 us; speedup vs baseline: 1.1166x; 1.1166x over previous
//
#include <hip/hip_runtime.h>
#include <hip/hip_bf16.h>

typedef unsigned short u16;
typedef __bf16 bf16x8 __attribute__((ext_vector_type(8)));
typedef float f32x4 __attribute__((ext_vector_type(4)));
typedef float f32x16 __attribute__((ext_vector_type(16)));
typedef unsigned short ushort8 __attribute__((ext_vector_type(8)));

#define C_IN   128
#define C_OUT  256
#define BATCH  16
#define LEN    4096
#define KS     9
#define PAD    4
#define LPAD   (LEN + 2*PAD)      // 4104
#define KTOT   (C_IN * KS)        // 1152
#define NSTEP  72                 // K = 1152 / 16

#define XT_BLKS    1040           // 65 * 16
#define W5_BLKS    1152           // 294912 / 256
#define EB_BLKS    256

__device__ inline u16 f2bf(float f) {
    __hip_bfloat16 h = __float2bfloat16(f);
    return __builtin_bit_cast(u16, h);
}

// async global->LDS, 16B per lane, wave-uniform LDS base + lane*16
__device__ __forceinline__ void g2l16(const void* g, void* l) {
    __builtin_amdgcn_global_load_lds(
        (const __attribute__((address_space(1))) void*)g,
        (__attribute__((address_space(3))) void*)l, 16, 0, 0);
}

// ---------------------------------------------------------------------------
// Fused prep (one launch) — UNCHANGED from R9/R10 (verified absmax 0.03125):
//  blocks [0,1040): x [B][C][L] f32 -> xt [B][LPAD][C] bf16, edge-padded,
//    4-bit XOR swizzle (16B-block idx ^= l&15) baked into global layout.
//  blocks [1040,2192): weight -> w5 in 32-lane fragment order for
//    mfma_f32_32x32x16_bf16:  i = ((s*8 + g)*64 + lane)*8 + e  where
//    o = g*32 + (lane&31), hi = lane>>5, c = (s&7)*16 + hi*8 + e, k = s>>3.
//  blocks [2192,2448): ebias[o] = bias[o] + sum offset*W; block 2192: phys.
// ---------------------------------------------------------------------------
__global__ void prep_all(const float* __restrict__ x, const float* __restrict__ w,
                         const float* __restrict__ bias, const float* __restrict__ vel,
                         const float* __restrict__ acc_in,
                         u16* __restrict__ xt, u16* __restrict__ w5,
                         float* __restrict__ ebias, float* __restrict__ phys_out) {
    int bid = blockIdx.x;
    int t = threadIdx.x;
    if (bid < XT_BLKS) {
        int b    = bid / 65;
        int lblk = bid % 65;
        int lane = t & 63;
        int jb   = t >> 6;
        int lp   = lblk * 64 + lane;
        if (lp >= LPAD) return;
        int l = lp - PAD;
        l = l < 0 ? 0 : (l > LEN - 1 ? LEN - 1 : l);
        const float* xb = x + (size_t)b * C_IN * LEN + l;
        u16* row = xt + ((size_t)b * LPAD + lp) * C_IN;
        int key = lp & 15;
        #pragma unroll
        for (int jj = 0; jj < 4; ++jj) {
            int cblk = jb * 4 + jj;
            ushort8 v;
            #pragma unroll
            for (int e = 0; e < 8; ++e)
                v[e] = f2bf(xb[(size_t)(cblk * 8 + e) * LEN]);
            int jstore = cblk ^ key;
            *reinterpret_cast<ushort8*>(row + jstore * 8) = v;
        }
        return;
    }
    if (bid < XT_BLKS + W5_BLKS) {
        int i = (bid - XT_BLKS) * 256 + t;   // 294912 total
        int e    = i & 7;
        int lane = (i >> 3) & 63;
        int g    = (i >> 9) & 7;
        int s    = i >> 12;                  // 0..71
        int o    = g * 32 + (lane & 31);
        int hi   = lane >> 5;
        int c    = (s & 7) * 16 + hi * 8 + e;
        int k    = s >> 3;
        w5[i] = f2bf(w[((size_t)o * C_IN + c) * KS + k]);
        return;
    }
    __shared__ float red[256];
    int o = bid - (XT_BLKS + W5_BLKS);
    float sum = 0.f;
    for (int i = t; i < KTOT; i += 256) {
        int k = i % KS;                    // offset layout [c][k]
        float tk = k * 0.01f;              // DT
        float off = vel[i] * tk + 0.5f * acc_in[i] * tk * tk;
        sum += off * w[(size_t)o * KTOT + i];
    }
    red[t] = sum;
    __syncthreads();
    for (int h = 128; h > 0; h >>= 1) {
        if (t < h) red[t] += red[t + h];
        __syncthreads();
    }
    if (t == 0) ebias[o] = bias[o] + red[0];

    if (o == 0) {                          // phys
        __syncthreads();
        float pv = 0.f;
        for (int i = t; i < KTOT; i += 256) {
            float v = vel[i], a = acc_in[i];
            pv += v * v + a * a;
        }
        red[t] = pv;
        __syncthreads();
        for (int h = 128; h > 0; h >>= 1) {
            if (t < h) red[t] += red[t + h];
            __syncthreads();
        }
        if (t == 0) *phys_out = 0.01f * (red[0] / (float)KTOT);
    }
}

// ---------------------------------------------------------------------------
// Main (REDESIGN): fat-wave, barrier-free K-loop.
// Wave tile 128o x 128l (acc[4][4] f32x16 = 256 regs, legal at 1 wave/SIMD:
// 512-reg budget, m69/m24). Block = 2 waves (wm 0/1) = 256o x 128l.
// Grid 512 = 2 blocks/CU -> one block's epilogue overlaps the other's MFMA.
// Machine balance per CU: MFMA 39.0 kcyc (16.2us floor) vs B-LDS-reads
// 13.8 kcyc vs A-global-issue tiny -> MFMA-bound by 2.8x.
//  - B (x-tile, 136 rows, 34816B) staged ONCE via g2l16; the ONLY barrier.
//  - A global->reg from L2-resident w5 (4 contiguous 1KB frags/wave/step,
//    wm-disjoint, no duplication), register dbuf at distance 1.
//  - B ds_read dbuf at distance 1. No mid-loop barrier/waitcnt asm: the
//    compiler's counted vmcnt/lgkmcnt before first use is exactly T4.
//  - Per-wave step wall = 16 MFMA ~ 541 cyc >> L2 (~250) and LDS (~150)
//    latency: distance-1 prefetch has 2x margin (R6 died at 1.0x).
// ---------------------------------------------------------------------------
__global__ __launch_bounds__(128, 1) void conv_main(const u16* __restrict__ xt,
                                                    const u16* __restrict__ w5,
                                                    const float* __restrict__ ebias,
                                                    float* __restrict__ out) {
    __shared__ u16 ldsx[17408];            // B tile: 136 rows x 256B = 34816 B

    int b     = blockIdx.y;
    int lbase = blockIdx.x * 128;
    int t     = threadIdx.x;               // 0..127
    int lane  = t & 63;
    int wm    = t >> 6;                    // wave = o-half (128 o each)
    int l31   = lane & 31;
    int hi    = lane >> 5;

    // A source: wave wm's 4 o-groups (g = wm*4+mi) -> contiguous 4KB/step
    const u16* alane = w5 + ((size_t)(wm * 4) * 64 + lane) * 8;

    #define LOAD_A(S, AF)                                                        \
        {                                                                        \
            const u16* p_ = alane + (size_t)(S) * 4096;                          \
            _Pragma("unroll")                                                    \
            for (int mi = 0; mi < 4; ++mi)                                       \
                AF[mi] = *reinterpret_cast<const bf16x8*>(p_ + mi * 512);        \
        }
    #define LOAD_B(S, BF)                                                        \
        {                                                                        \
            int k_ = (S) >> 3;                                                   \
            int sl_ = ((S) & 7) * 2 + hi;                                        \
            _Pragma("unroll")                                                    \
            for (int nj = 0; nj < 4; ++nj) {                                     \
                int row_  = nj * 32 + l31 + k_;                                  \
                int addr_ = row_ * 256 + ((sl_ ^ (row_ & 15)) << 4);             \
                BF[nj] = *reinterpret_cast<const bf16x8*>(ldsbase + addr_);      \
            }                                                                    \
        }
    #define MFMA16(AF, BF)                                                       \
        {                                                                        \
            _Pragma("unroll")                                                    \
            for (int mi = 0; mi < 4; ++mi)                                       \
                _Pragma("unroll")                                                \
                for (int nj = 0; nj < 4; ++nj)                                   \
                    acc[mi][nj] = __builtin_amdgcn_mfma_f32_32x32x16_bf16(       \
                        AF[mi], BF[nj], acc[mi][nj], 0, 0, 0);                   \
        }

    bf16x8 aA[4], aB[4], bA[4], bB[4];

    // ---- prologue: stage B tile (2176 16B-units, 17 calls x 128 threads)
    {
        const u16* bsrc = xt + ((size_t)b * LPAD + lbase) * C_IN;
        #pragma unroll
        for (int j = 0; j < 17; ++j)
            g2l16(bsrc + (j * 128 + t) * 8, ldsx + (j * 128 + wm * 64) * 8);
    }
    LOAD_A(0, aA);                         // independent of LDS; issue early
    __syncthreads();                       // drains staging; the only barrier

    f32x16 acc[4][4] = {};
    const char* ldsbase = reinterpret_cast<const char*>(ldsx);
    LOAD_B(0, bA);

    #pragma unroll
    for (int s = 0; s < NSTEP; s += 2) {
        LOAD_A(s + 1, aB);
        LOAD_B(s + 1, bB);
        MFMA16(aA, bA);
        if (s + 2 < NSTEP) { LOAD_A(s + 2, aA); LOAD_B(s + 2, bA); }
        MFMA16(aB, bB);
    }

    // ---- epilogue: 32x32 D layout col = lane&31 (l), row = (reg&3)+8*(reg>>2)+4*hi
    #pragma unroll
    for (int mi = 0; mi < 4; ++mi) {
        int o0 = wm * 128 + mi * 32 + hi * 4;
        #pragma unroll
        for (int nj = 0; nj < 4; ++nj) {
            int l = lbase + nj * 32 + l31;
            #pragma unroll
            for (int q = 0; q < 4; ++q) {
                f32x4 eb = *reinterpret_cast<const f32x4*>(ebias + o0 + q * 8);
                float* op = out + (size_t)(b * C_OUT + o0 + q * 8) * LEN + l;
                #pragma unroll
                for (int p = 0; p < 4; ++p)
                    op[(size_t)p * LEN] = acc[mi][nj][q * 4 + p] + eb[p];
            }
        }
    }
    #undef LOAD_A
    #undef LOAD_B
    #undef MFMA16
}

extern "C" void kernel_launch(void* const* d_in, const int* in_sizes, int n_in,
                              void* d_out, int out_size, void* d_ws, size_t ws_size,
                              hipStream_t stream) {
    const float* x      = (const float*)d_in[0];
    const float* weight = (const float*)d_in[1];
    const float* bias   = (const float*)d_in[2];
    const float* vel    = (const float*)d_in[3];
    const float* acc    = (const float*)d_in[4];
    float* out = (float*)d_out;

    char* ws = (char*)d_ws;
    u16*  xt    = (u16*)ws;                                       // 16,797,696 B
    u16*  w5    = (u16*)(ws + (size_t)BATCH * LPAD * C_IN * 2);   // 589,824 B
    float* ebias = (float*)(ws + (size_t)BATCH * LPAD * C_IN * 2 + (size_t)C_OUT * KTOT * 2);

    hipLaunchKernelGGL(prep_all, dim3(XT_BLKS + W5_BLKS + EB_BLKS), dim3(256), 0, stream,
                       x, weight, bias, vel, acc, xt, w5, ebias,
                       out + (size_t)BATCH * C_OUT * LEN);
    hipLaunchKernelGGL(conv_main, dim3(LEN / 128, BATCH), dim3(128), 0, stream,
                       xt, w5, ebias, out);
}